// Round 1
// baseline (1072.345 us; speedup 1.0000x reference)
//
#include <hip/hip_runtime.h>
#include <math.h>

// Sizes (fixed by the problem)
#define B_  64
#define L_  48
#define E_  300
#define F0_ 300
#define NEGP (-1e30f)

// -------- workspace layout (float offsets) --------
// r1   : 0        .. 921600      (B*L*E)
// r2   : 921600   .. 1843200
// s1p  : 1843200  .. 4608000     (B*3*48*300)  pre-tanh partial max over j per j-tile
// s2p  : 4608000  .. 7372800     (B*3*48*300)  pre-tanh partial max over i per i-tile
// s1   : 7372800  .. 8294400
// s2   : 8294400  .. 9216000
// h1   : 9216000  .. 9235200
// h2   : 9235200  .. 9254400
// wt   : 9254400  .. 9524400     transposed conv weights [k][i][o]

// K0: transpose conv_w (E,E,3)->[k][i][o] for coalesced reads in K1
__global__ void k0_transpose_w(const float* __restrict__ conv_w, float* __restrict__ wt) {
    int idx = blockIdx.x * 256 + threadIdx.x;
    if (idx >= 3 * E_ * E_) return;
    int o = idx % E_;
    int rest = idx / E_;
    int i = rest % E_;
    int k = rest / E_;
    wt[idx] = conv_w[(o * E_ + i) * 3 + k];   // wt[(k*300+i)*300+o]
}

// K1: r[side][b,l,o] = tanh(conv_b[o] + sum_{i,k} emb[q[b,l+k-1],i]*w[o,i,k])
// one block per (side,b,l-half of 24); thread owns output channel o for all 24 l.
__global__ __launch_bounds__(320) void k1_encode(
    const int* __restrict__ q1, const int* __restrict__ q2,
    const float* __restrict__ emb, const float* __restrict__ wt,
    const float* __restrict__ conv_b, float* __restrict__ r1, float* __restrict__ r2)
{
    int x = blockIdx.x;
    int lh = x & 1;
    int b = (x >> 1) & 63;
    int side = x >> 7;
    const int* q = side ? q2 : q1;
    float* rout = side ? r2 : r1;
    int l0 = lh * 24;
    __shared__ __align__(16) float xs[300 * 28];   // [i][r], r = local row 0..25 -> l = l0-1+r
    int tid = threadIdx.x;
    for (int idx = tid; idx < 26 * 300; idx += 320) {
        int r = idx / 300;
        int i = idx - r * 300;
        int l = l0 - 1 + r;
        float v = 0.f;
        if (l >= 0 && l < 48) v = emb[(long)q[b * 48 + l] * 300 + i];
        xs[i * 28 + r] = v;
    }
    __syncthreads();
    int o = tid;
    if (o < 300) {
        float acc[24];
        float bias = conv_b[o];
#pragma unroll
        for (int l = 0; l < 24; ++l) acc[l] = bias;
        for (int i = 0; i < 300; ++i) {
            float xf[28];
#pragma unroll
            for (int t = 0; t < 7; ++t) {
                float4 v4 = *reinterpret_cast<const float4*>(&xs[i * 28 + t * 4]);
                xf[t * 4 + 0] = v4.x; xf[t * 4 + 1] = v4.y;
                xf[t * 4 + 2] = v4.z; xf[t * 4 + 3] = v4.w;
            }
#pragma unroll
            for (int k = 0; k < 3; ++k) {
                float w = wt[(k * 300 + i) * 300 + o];
#pragma unroll
                for (int l = 0; l < 24; ++l) acc[l] = fmaf(xf[l + k], w, acc[l]);
            }
        }
#pragma unroll
        for (int l = 0; l < 24; ++l)
            rout[(long)(b * 48 + l0 + l) * 300 + o] = tanhf(acc[l]);
    }
}

// K2: pre[b,i,j,f] = sum_{e<300} |r1-r2|*Wd + sum r1*r2*Wp  (no bias/tanh here!)
// masked max over j -> s1p[b][jt][i][f]; masked max over i -> s2p[b][it][j][f].
// Block = (b, it, jt) 16x16 pair tile; thread owns 8 j x 8 f accumulators.
__global__ __launch_bounds__(256, 2) void k2_joint(
    const float* __restrict__ r1, const float* __restrict__ r2,
    const int* __restrict__ q1_len, const int* __restrict__ q2_len,
    const float* __restrict__ fc0w,
    float* __restrict__ s1p, float* __restrict__ s2p)
{
    int b = blockIdx.y;
    int it = blockIdx.x / 3;
    int jt = blockIdx.x - it * 3;
    int tid = threadIdx.x;
    int q1l = q1_len[b], q2l = q2_len[b];
    long base1 = ((long)(b * 3 + jt) * 48 + it * 16) * 300;
    long base2 = ((long)(b * 3 + it) * 48 + jt * 16) * 300;
    bool active = (it * 16 < q1l) && (jt * 16 < q2l);
    if (!active) {
        // no valid pair in this tile: partials are identity (-1e30)
        for (int idx = tid; idx < 4800; idx += 256) {
            s1p[base1 + idx] = NEGP;
            s2p[base2 + idx] = NEGP;
        }
        return;
    }
    __shared__ __align__(16) float sm[15152];
    float* r1t  = sm;                 // [16][300]
    float* r2tT = sm + 4800;          // [300][20] transposed, padded
    float* BtR  = sm + 10800;         // union: Bt [30][68] / red [64][68]

    for (int idx = tid; idx < 4800; idx += 256)
        r1t[idx] = r1[((long)(b * 48) + it * 16) * 300 + idx];
    for (int idx = tid; idx < 4800; idx += 256) {
        int j = idx / 300;
        int e = idx - j * 300;
        r2tT[e * 20 + j] = r2[((long)(b * 48) + jt * 16 + j) * 300 + e];
    }

    int fg = tid & 7;            // f-group (8 f each)
    int jh = (tid >> 3) & 1;     // j-half (8 j each)
    int ii = tid >> 4;           // i in [0,16)
    int wv = tid >> 6;
    int lane = tid & 63;
    float acc[8][8];             // [j][f]

    for (int fc = 0; fc < 5; ++fc) {
        int f0 = fc * 64;
#pragma unroll
        for (int k = 0; k < 8; ++k)
#pragma unroll
            for (int m = 0; m < 8; ++m) acc[k][m] = 0.f;

        for (int ec = 0; ec < 20; ++ec) {
            int e0 = ec * 30;
            __syncthreads();
            for (int sidx = tid; sidx < 1920; sidx += 256) {
                int f = sidx / 30;
                int es = sidx - f * 30;
                int fglob = f0 + f;
                float v = 0.f;
                if (fglob < 300) v = fc0w[fglob * 600 + e0 + es];
                BtR[es * 68 + f] = v;
            }
            __syncthreads();
            const float* r1row = r1t + ii * 300;
            if (e0 < 300) {
                // d-part: |r1 - r2|
#pragma unroll 2
                for (int es = 0; es < 30; ++es) {
                    int er = e0 + es;
                    float r1v = r1row[er];
                    float4 ra = *reinterpret_cast<const float4*>(&r2tT[er * 20 + jh * 8]);
                    float4 rb = *reinterpret_cast<const float4*>(&r2tT[er * 20 + jh * 8 + 4]);
                    float4 ba = *reinterpret_cast<const float4*>(&BtR[es * 68 + fg * 8]);
                    float4 bb = *reinterpret_cast<const float4*>(&BtR[es * 68 + fg * 8 + 4]);
                    float av[8] = {fabsf(r1v - ra.x), fabsf(r1v - ra.y), fabsf(r1v - ra.z), fabsf(r1v - ra.w),
                                   fabsf(r1v - rb.x), fabsf(r1v - rb.y), fabsf(r1v - rb.z), fabsf(r1v - rb.w)};
                    float bv[8] = {ba.x, ba.y, ba.z, ba.w, bb.x, bb.y, bb.z, bb.w};
#pragma unroll
                    for (int k = 0; k < 8; ++k)
#pragma unroll
                        for (int m = 0; m < 8; ++m)
                            acc[k][m] = fmaf(av[k], bv[m], acc[k][m]);
                }
            } else {
                // p-part: r1 * r2
#pragma unroll 2
                for (int es = 0; es < 30; ++es) {
                    int er = e0 + es - 300;
                    float r1v = r1row[er];
                    float4 ra = *reinterpret_cast<const float4*>(&r2tT[er * 20 + jh * 8]);
                    float4 rb = *reinterpret_cast<const float4*>(&r2tT[er * 20 + jh * 8 + 4]);
                    float4 ba = *reinterpret_cast<const float4*>(&BtR[es * 68 + fg * 8]);
                    float4 bb = *reinterpret_cast<const float4*>(&BtR[es * 68 + fg * 8 + 4]);
                    float av[8] = {r1v * ra.x, r1v * ra.y, r1v * ra.z, r1v * ra.w,
                                   r1v * rb.x, r1v * rb.y, r1v * rb.z, r1v * rb.w};
                    float bv[8] = {ba.x, ba.y, ba.z, ba.w, bb.x, bb.y, bb.z, bb.w};
#pragma unroll
                    for (int k = 0; k < 8; ++k)
#pragma unroll
                        for (int m = 0; m < 8; ++m)
                            acc[k][m] = fmaf(av[k], bv[m], acc[k][m]);
                }
            }
        }

        // ---- s1: max over valid j (this tile) ----
        int njv = q2l - jt * 16 - jh * 8;   // valid j count within this thread's 8
#pragma unroll
        for (int m = 0; m < 8; ++m) {
            float v = NEGP;
#pragma unroll
            for (int k = 0; k < 8; ++k)
                if (k < njv) v = fmaxf(v, acc[k][m]);
            v = fmaxf(v, __shfl_xor(v, 8));
            if (jh == 0) {
                int f = f0 + fg * 8 + m;
                if (f < 300) s1p[base1 + ii * 300 + f] = v;
            }
        }

        // ---- s2: max over valid i (this tile) ----
        bool iok = (it * 16 + ii) < q1l;
        float* red = BtR;  // alias (Bt dead until next f-chunk restage)
        __syncthreads();
#pragma unroll
        for (int k = 0; k < 8; ++k) {
#pragma unroll
            for (int m = 0; m < 8; ++m) {
                float v = iok ? acc[k][m] : NEGP;
                v = fmaxf(v, __shfl_xor(v, 16));
                v = fmaxf(v, __shfl_xor(v, 32));
                if (lane < 16) red[(wv * 16 + lane) * 68 + k * 8 + m] = v;
            }
        }
        __syncthreads();
        for (int vv = tid; vv < 1024; vv += 256) {
            int j = vv >> 6;
            int f = vv & 63;
            int off = ((j >> 3) * 8 + (f >> 3)) * 68 + (j & 7) * 8 + (f & 7);
            float v = red[off];
            v = fmaxf(v, red[16 * 68 + off]);
            v = fmaxf(v, red[32 * 68 + off]);
            v = fmaxf(v, red[48 * 68 + off]);
            int fglob = f0 + f;
            if (fglob < 300) s2p[base2 + (long)j * 300 + fglob] = v;
        }
        // leading __syncthreads of next ec-loop protects red vs Bt restage
    }
}

// K3: s = tanh(bias + max over 3 tile-partials)
__global__ void k3_combine(const float* __restrict__ s1p, const float* __restrict__ s2p,
                           const float* __restrict__ fc0b,
                           float* __restrict__ s1, float* __restrict__ s2)
{
    int idx = blockIdx.x * 256 + threadIdx.x;
    if (idx >= 64 * 48 * 300) return;
    int b = idx / 14400;
    int lf = idx - b * 14400;
    int f = lf % 300;
    long p = (long)b * 43200 + lf;
    float m1v = fmaxf(fmaxf(s1p[p], s1p[p + 14400]), s1p[p + 28800]);
    float m2v = fmaxf(fmaxf(s2p[p], s2p[p + 14400]), s2p[p + 28800]);
    float bia = fc0b[f];
    s1[idx] = tanhf(m1v + bia);
    s2[idx] = tanhf(m2v + bia);
}

// K4: attention pooling per (side,b): one wave
__global__ __launch_bounds__(64) void k4_pool(
    const float* __restrict__ r1, const float* __restrict__ r2,
    const float* __restrict__ s1, const float* __restrict__ s2,
    const int* __restrict__ q1_len, const int* __restrict__ q2_len,
    const float* __restrict__ att_w, const float* __restrict__ att_b,
    float* __restrict__ h1, float* __restrict__ h2)
{
    int side = blockIdx.x >> 6;
    int b = blockIdx.x & 63;
    const float* r = (side ? r2 : r1) + (long)b * 48 * 300;
    const float* s = (side ? s2 : s1) + (long)b * 48 * 300;
    int len = (side ? q2_len : q1_len)[b];
    float* h = (side ? h2 : h1) + b * 300;
    int t = threadIdx.x;
    __shared__ float aL[48];
    float logit = 0.f;
    if (t < 48) {
        float acc = att_b[0];
        for (int e = 0; e < 300; ++e) acc += r[t * 300 + e] * att_w[e];
        for (int f = 0; f < 300; ++f) acc += s[t * 300 + f] * att_w[300 + f];
        logit = acc;
    }
    float ml = (t < len) ? logit : NEGP;
    float mx = ml;
#pragma unroll
    for (int off = 32; off >= 1; off >>= 1) mx = fmaxf(mx, __shfl_xor(mx, off));
    float ex = (t < len) ? __expf(logit - mx) : 0.f;
    float smv = ex;
#pragma unroll
    for (int off = 32; off >= 1; off >>= 1) smv += __shfl_xor(smv, off);
    if (t < 48) aL[t] = ex / smv;
    __syncthreads();
    for (int f = t; f < 300; f += 64) {
        float acc = 0.f;
        for (int l = 0; l < 48; ++l) acc += aL[l] * s[(long)l * 300 + f];
        h[f] = acc;
    }
}

// K5: final MLP per batch row
__global__ __launch_bounds__(256) void k5_mlp(
    const float* __restrict__ h1, const float* __restrict__ h2,
    const float* __restrict__ fc1w, const float* __restrict__ fc1b,
    const float* __restrict__ fc2w, const float* __restrict__ fc2b,
    float* __restrict__ out)
{
    int b = blockIdx.x;
    int t = threadIdx.x;
    __shared__ float hc[600];
    __shared__ float jl[300];
    for (int e = t; e < 600; e += 256)
        hc[e] = (e < 300) ? h1[b * 300 + e] : h2[b * 300 + e - 300];
    __syncthreads();
    for (int g = t; g < 300; g += 256) {
        float acc = fc1b[g];
        for (int e = 0; e < 600; ++e) acc += hc[e] * fc1w[g * 600 + e];
        jl[g] = tanhf(acc);
    }
    __syncthreads();
    int wvv = t >> 6, lane = t & 63;
    if (wvv < 2) {
        float acc = 0.f;
        for (int g = lane; g < 300; g += 64) acc += jl[g] * fc2w[wvv * 300 + g];
#pragma unroll
        for (int off = 32; off >= 1; off >>= 1) acc += __shfl_xor(acc, off);
        if (lane == 0) out[b * 2 + wvv] = acc + fc2b[wvv];
    }
}

extern "C" void kernel_launch(void* const* d_in, const int* in_sizes, int n_in,
                              void* d_out, int out_size, void* d_ws, size_t ws_size,
                              hipStream_t stream)
{
    const int*   q1     = (const int*)d_in[0];
    const int*   q2     = (const int*)d_in[1];
    const int*   q1_len = (const int*)d_in[2];
    const int*   q2_len = (const int*)d_in[3];
    const float* emb    = (const float*)d_in[4];
    const float* conv_w = (const float*)d_in[5];
    const float* conv_b = (const float*)d_in[6];
    const float* fc0_w  = (const float*)d_in[7];
    const float* fc0_b  = (const float*)d_in[8];
    const float* fc1_w  = (const float*)d_in[9];
    const float* fc1_b  = (const float*)d_in[10];
    const float* fc2_w  = (const float*)d_in[11];
    const float* fc2_b  = (const float*)d_in[12];
    const float* att_w  = (const float*)d_in[13];
    const float* att_b  = (const float*)d_in[14];

    float* ws  = (float*)d_ws;
    float* r1  = ws;
    float* r2  = ws + 921600;
    float* s1p = ws + 1843200;
    float* s2p = ws + 4608000;
    float* s1  = ws + 7372800;
    float* s2  = ws + 8294400;
    float* h1  = ws + 9216000;
    float* h2  = ws + 9235200;
    float* wt  = ws + 9254400;
    float* out = (float*)d_out;

    hipLaunchKernelGGL(k0_transpose_w, dim3((3 * E_ * E_ + 255) / 256), dim3(256), 0, stream,
                       conv_w, wt);
    hipLaunchKernelGGL(k1_encode, dim3(256), dim3(320), 0, stream,
                       q1, q2, emb, wt, conv_b, r1, r2);
    hipLaunchKernelGGL(k2_joint, dim3(9, 64), dim3(256), 0, stream,
                       r1, r2, q1_len, q2_len, fc0_w, s1p, s2p);
    hipLaunchKernelGGL(k3_combine, dim3((64 * 48 * 300 + 255) / 256), dim3(256), 0, stream,
                       s1p, s2p, fc0_b, s1, s2);
    hipLaunchKernelGGL(k4_pool, dim3(128), dim3(64), 0, stream,
                       r1, r2, s1, s2, q1_len, q2_len, att_w, att_b, h1, h2);
    hipLaunchKernelGGL(k5_mlp, dim3(64), dim3(256), 0, stream,
                       h1, h2, fc1_w, fc1_b, fc2_w, fc2_b, out);
}

// Round 2
// 413.820 us; speedup vs baseline: 2.5913x; 2.5913x over previous
//
#include <hip/hip_runtime.h>
#include <math.h>

// Sizes (fixed by the problem)
#define B_  64
#define L_  48
#define E_  300
#define F0_ 300
#define NEGP (-1e30f)

typedef __attribute__((ext_vector_type(8))) _Float16 half8;
typedef __attribute__((ext_vector_type(8))) short   short8;
typedef __attribute__((ext_vector_type(4))) float   float4v;

// -------- workspace layout (float offsets) --------
// r1   : 0        .. 921600      (B*L*E)
// r2   : 921600   .. 1843200
// s1p  : 1843200  .. 4608000     (B*3*48*300)  pre-tanh partial max over j per j-tile
// s2p  : 4608000  .. 7372800     (B*3*48*300)  pre-tanh partial max over i per i-tile
// s1   : 7372800  .. 8294400
// s2   : 8294400  .. 9216000
// h1   : 9216000  .. 9235200
// h2   : 9235200  .. 9254400
// wt   : 9254400  .. 9524400     transposed conv weights [k][i][o]

// K0: transpose conv_w (E,E,3)->[k][i][o] for coalesced reads in K1
__global__ void k0_transpose_w(const float* __restrict__ conv_w, float* __restrict__ wt) {
    int idx = blockIdx.x * 256 + threadIdx.x;
    if (idx >= 3 * E_ * E_) return;
    int o = idx % E_;
    int rest = idx / E_;
    int i = rest % E_;
    int k = rest / E_;
    wt[idx] = conv_w[(o * E_ + i) * 3 + k];   // wt[(k*300+i)*300+o]
}

// K1: r[side][b,l,o] = tanh(conv_b[o] + sum_{i,k} emb[q[b,l+k-1],i]*w[o,i,k])
__global__ __launch_bounds__(320) void k1_encode(
    const int* __restrict__ q1, const int* __restrict__ q2,
    const float* __restrict__ emb, const float* __restrict__ wt,
    const float* __restrict__ conv_b, float* __restrict__ r1, float* __restrict__ r2)
{
    int x = blockIdx.x;
    int lh = x & 1;
    int b = (x >> 1) & 63;
    int side = x >> 7;
    const int* q = side ? q2 : q1;
    float* rout = side ? r2 : r1;
    int l0 = lh * 24;
    __shared__ __align__(16) float xs[300 * 28];
    int tid = threadIdx.x;
    for (int idx = tid; idx < 26 * 300; idx += 320) {
        int r = idx / 300;
        int i = idx - r * 300;
        int l = l0 - 1 + r;
        float v = 0.f;
        if (l >= 0 && l < 48) v = emb[(long)q[b * 48 + l] * 300 + i];
        xs[i * 28 + r] = v;
    }
    __syncthreads();
    int o = tid;
    if (o < 300) {
        float acc[24];
        float bias = conv_b[o];
#pragma unroll
        for (int l = 0; l < 24; ++l) acc[l] = bias;
        for (int i = 0; i < 300; ++i) {
            float xf[28];
#pragma unroll
            for (int t = 0; t < 7; ++t) {
                float4 v4 = *reinterpret_cast<const float4*>(&xs[i * 28 + t * 4]);
                xf[t * 4 + 0] = v4.x; xf[t * 4 + 1] = v4.y;
                xf[t * 4 + 2] = v4.z; xf[t * 4 + 3] = v4.w;
            }
#pragma unroll
            for (int k = 0; k < 3; ++k) {
                float w = wt[(k * 300 + i) * 300 + o];
#pragma unroll
                for (int l = 0; l < 24; ++l) acc[l] = fmaf(xf[l + k], w, acc[l]);
            }
        }
#pragma unroll
        for (int l = 0; l < 24; ++l)
            rout[(long)(b * 48 + l0 + l) * 300 + o] = tanhf(acc[l]);
    }
}

// ---------------------------------------------------------------------------
// K2 (MFMA): pre[b,i,j,f] = sum_e |r1-r2|*Wd + sum_e r1*r2*Wp  (no bias/tanh)
// GEMM view per block (b,it,jt): [256 pairs] x [K=608] x [304 f]
//   pair p = i_local*16 + j_local  -> m-tile = i_local, row-in-tile = j_local
//   K axis: k in [0,304) = d-part (e=k, 300..303 zero-pad)
//           k in [304,604) = p-part (e=k-304), [604,608) zero-pad
// A-fragments generated in registers from fp16 r-tiles in LDS.
// ---------------------------------------------------------------------------
#define RS 312   // LDS row stride (halves) for r tiles: 624B, 16B-aligned, 2-way banks

__global__ __launch_bounds__(256, 2) void k2_joint(
    const float* __restrict__ r1, const float* __restrict__ r2,
    const int* __restrict__ q1_len, const int* __restrict__ q2_len,
    const float* __restrict__ fc0w,
    float* __restrict__ s1p, float* __restrict__ s2p)
{
    int b = blockIdx.y;
    int it = blockIdx.x / 3;
    int jt = blockIdx.x - it * 3;
    int tid = threadIdx.x;
    int q1l = q1_len[b], q2l = q2_len[b];
    long base1 = ((long)(b * 3 + jt) * 48 + it * 16) * 300;
    long base2 = ((long)(b * 3 + it) * 48 + jt * 16) * 300;
    bool active = (it * 16 < q1l) && (jt * 16 < q2l);
    if (!active) {
        for (int idx = tid; idx < 4800; idx += 256) {
            s1p[base1 + idx] = NEGP;
            s2p[base2 + idx] = NEGP;
        }
        return;
    }

    __shared__ __align__(16) unsigned char smraw[16 * RS * 2 * 2 + 17408];
    _Float16* r1h = (_Float16*)smraw;            // [16][RS]
    _Float16* r2h = r1h + 16 * RS;               // [16][RS]
    _Float16* Bt  = r2h + 16 * RS;               // [64][40] halves (union with red)
    float*    red = (float*)(r2h + 16 * RS);     // [64][68] floats (union with Bt)

    // stage r tiles -> fp16 LDS (single copy; p-part re-reads same values)
    for (int idx = tid; idx < 4800; idx += 256) {
        int row = idx / 300;
        int e = idx - row * 300;
        r1h[row * RS + e] = (_Float16)r1[((long)(b * 48) + it * 16) * 300 + idx];
        r2h[row * RS + e] = (_Float16)r2[((long)(b * 48) + jt * 16) * 300 + idx];
    }
    // zero-pad e in [300, RS)
    for (int idx = tid; idx < 2 * 16 * (RS - 300); idx += 256) {
        int half = idx / (16 * (RS - 300));
        int rest = idx - half * 16 * (RS - 300);
        int row = rest / (RS - 300);
        int e = 300 + rest - row * (RS - 300);
        (half ? r2h : r1h)[row * RS + e] = (_Float16)0.f;
    }

    int w    = tid >> 6;        // wave 0..3  -> owns i_locals w*4..w*4+3
    int lane = tid & 63;
    int q    = lane >> 4;       // quad
    int jcol = lane & 15;       // = j_local for A-frags, = f-col for B-frags/D

    // Bt vector-staging indices: thread -> (f_l, k8)
    int sf_l = tid >> 2;
    int sk8  = (tid & 3) * 8;

    float4v acc[4][4];

    for (int nc = 0; nc < 5; ++nc) {
#pragma unroll
        for (int mt = 0; mt < 4; ++mt)
#pragma unroll
            for (int nt = 0; nt < 4; ++nt)
                acc[mt][nt] = (float4v){0.f, 0.f, 0.f, 0.f};

        for (int kc = 0; kc < 19; ++kc) {
            __syncthreads();   // protect Bt (prev iter readers / red users)
            // ---- stage B chunk: Bt[f_l][k_l] = W[k][f], fp16 ----
            {
                int f = nc * 64 + sf_l;
                int kbase = kc * 32 + sk8;
                half8 hv;
                if (f < 300) {
                    const float* rowp = fc0w + f * 600;
                    if (kbase + 7 < 300) {
#pragma unroll
                        for (int e = 0; e < 8; ++e) hv[e] = (_Float16)rowp[kbase + e];
                    } else if (kbase >= 304 && kbase + 7 < 604) {
#pragma unroll
                        for (int e = 0; e < 8; ++e) hv[e] = (_Float16)rowp[kbase - 4 + e];
                    } else {
#pragma unroll
                        for (int e = 0; e < 8; ++e) {
                            int k = kbase + e;
                            float v = 0.f;
                            if (k < 300) v = rowp[k];
                            else if (k >= 304 && k < 604) v = rowp[k - 4];
                            hv[e] = (_Float16)v;
                        }
                    }
                } else {
#pragma unroll
                    for (int e = 0; e < 8; ++e) hv[e] = (_Float16)0.f;
                }
                *reinterpret_cast<half8*>(Bt + sf_l * 40 + sk8) = hv;
            }
            __syncthreads();

            // ---- generate A-frags in registers + load B-frags ----
            int k0q = kc * 32 + q * 8;
            int koff = (k0q < 304) ? k0q : (k0q - 304);
            const half8 rv2 = *reinterpret_cast<const half8*>(r2h + jcol * RS + koff);
            half8 afr[4];
#pragma unroll
            for (int mt = 0; mt < 4; ++mt) {
                const half8 rv1 = *reinterpret_cast<const half8*>(r1h + (w * 4 + mt) * RS + koff);
                if (k0q < 304) {
                    half8 dsub = rv1 - rv2;
                    short8 s;
                    __builtin_memcpy(&s, &dsub, 16);
                    s &= (short)0x7FFF;
                    __builtin_memcpy(&afr[mt], &s, 16);
                } else {
                    afr[mt] = rv1 * rv2;
                }
            }
            half8 bfr[4];
#pragma unroll
            for (int nt = 0; nt < 4; ++nt)
                bfr[nt] = *reinterpret_cast<const half8*>(Bt + (nt * 16 + jcol) * 40 + q * 8);
#pragma unroll
            for (int mt = 0; mt < 4; ++mt)
#pragma unroll
                for (int nt = 0; nt < 4; ++nt)
                    acc[mt][nt] = __builtin_amdgcn_mfma_f32_16x16x32_f16(
                        afr[mt], bfr[nt], acc[mt][nt], 0, 0, 0);
        }

        // ---- s1: max over valid j (rows of each m-tile) ----
#pragma unroll
        for (int mt = 0; mt < 4; ++mt) {
            int i_l = w * 4 + mt;
#pragma unroll
            for (int nt = 0; nt < 4; ++nt) {
                float m = NEGP;
#pragma unroll
                for (int r = 0; r < 4; ++r) {
                    int j = q * 4 + r;
                    if (jt * 16 + j < q2l) m = fmaxf(m, acc[mt][nt][r]);
                }
                m = fmaxf(m, __shfl_xor(m, 16));
                m = fmaxf(m, __shfl_xor(m, 32));
                int f = nc * 64 + nt * 16 + jcol;
                if (q == 0 && f < 300) s1p[base1 + i_l * 300 + f] = m;
            }
        }

        // ---- s2: max over valid i (m-tiles), cross-wave via LDS ----
        __syncthreads();   // all waves done reading Bt before red overwrites it
#pragma unroll
        for (int nt = 0; nt < 4; ++nt) {
#pragma unroll
            for (int r = 0; r < 4; ++r) {
                float m = NEGP;
#pragma unroll
                for (int mt = 0; mt < 4; ++mt) {
                    int i = it * 16 + w * 4 + mt;
                    if (i < q1l) m = fmaxf(m, acc[mt][nt][r]);
                }
                red[((w * 16) + q * 4 + r) * 68 + nt * 16 + jcol] = m;
            }
        }
        __syncthreads();
        for (int vv = tid; vv < 1024; vv += 256) {
            int j = vv >> 6;
            int fcol = vv & 63;
            float m = red[(j)*68 + fcol];
            m = fmaxf(m, red[(16 + j) * 68 + fcol]);
            m = fmaxf(m, red[(32 + j) * 68 + fcol]);
            m = fmaxf(m, red[(48 + j) * 68 + fcol]);
            int f = nc * 64 + fcol;
            if (f < 300) s2p[base2 + (long)j * 300 + f] = m;
        }
        // next nc's first __syncthreads protects red vs Bt restage
    }
}

// K3: s = tanh(bias + max over 3 tile-partials)
__global__ void k3_combine(const float* __restrict__ s1p, const float* __restrict__ s2p,
                           const float* __restrict__ fc0b,
                           float* __restrict__ s1, float* __restrict__ s2)
{
    int idx = blockIdx.x * 256 + threadIdx.x;
    if (idx >= 64 * 48 * 300) return;
    int b = idx / 14400;
    int lf = idx - b * 14400;
    int f = lf % 300;
    long p = (long)b * 43200 + lf;
    float m1v = fmaxf(fmaxf(s1p[p], s1p[p + 14400]), s1p[p + 28800]);
    float m2v = fmaxf(fmaxf(s2p[p], s2p[p + 14400]), s2p[p + 28800]);
    float bia = fc0b[f];
    s1[idx] = tanhf(m1v + bia);
    s2[idx] = tanhf(m2v + bia);
}

// K4: attention pooling per (side,b): one wave
__global__ __launch_bounds__(64) void k4_pool(
    const float* __restrict__ r1, const float* __restrict__ r2,
    const float* __restrict__ s1, const float* __restrict__ s2,
    const int* __restrict__ q1_len, const int* __restrict__ q2_len,
    const float* __restrict__ att_w, const float* __restrict__ att_b,
    float* __restrict__ h1, float* __restrict__ h2)
{
    int side = blockIdx.x >> 6;
    int b = blockIdx.x & 63;
    const float* r = (side ? r2 : r1) + (long)b * 48 * 300;
    const float* s = (side ? s2 : s1) + (long)b * 48 * 300;
    int len = (side ? q2_len : q1_len)[b];
    float* h = (side ? h2 : h1) + b * 300;
    int t = threadIdx.x;
    __shared__ float aL[48];
    float logit = 0.f;
    if (t < 48) {
        float acc = att_b[0];
        for (int e = 0; e < 300; ++e) acc += r[t * 300 + e] * att_w[e];
        for (int f = 0; f < 300; ++f) acc += s[t * 300 + f] * att_w[300 + f];
        logit = acc;
    }
    float ml = (t < len) ? logit : NEGP;
    float mx = ml;
#pragma unroll
    for (int off = 32; off >= 1; off >>= 1) mx = fmaxf(mx, __shfl_xor(mx, off));
    float ex = (t < len) ? __expf(logit - mx) : 0.f;
    float smv = ex;
#pragma unroll
    for (int off = 32; off >= 1; off >>= 1) smv += __shfl_xor(smv, off);
    if (t < 48) aL[t] = ex / smv;
    __syncthreads();
    for (int f = t; f < 300; f += 64) {
        float acc = 0.f;
        for (int l = 0; l < 48; ++l) acc += aL[l] * s[(long)l * 300 + f];
        h[f] = acc;
    }
}

// K5: final MLP per batch row
__global__ __launch_bounds__(256) void k5_mlp(
    const float* __restrict__ h1, const float* __restrict__ h2,
    const float* __restrict__ fc1w, const float* __restrict__ fc1b,
    const float* __restrict__ fc2w, const float* __restrict__ fc2b,
    float* __restrict__ out)
{
    int b = blockIdx.x;
    int t = threadIdx.x;
    __shared__ float hc[600];
    __shared__ float jl[300];
    for (int e = t; e < 600; e += 256)
        hc[e] = (e < 300) ? h1[b * 300 + e] : h2[b * 300 + e - 300];
    __syncthreads();
    for (int g = t; g < 300; g += 256) {
        float acc = fc1b[g];
        for (int e = 0; e < 600; ++e) acc += hc[e] * fc1w[g * 600 + e];
        jl[g] = tanhf(acc);
    }
    __syncthreads();
    int wvv = t >> 6, lane = t & 63;
    if (wvv < 2) {
        float acc = 0.f;
        for (int g = lane; g < 300; g += 64) acc += jl[g] * fc2w[wvv * 300 + g];
#pragma unroll
        for (int off = 32; off >= 1; off >>= 1) acc += __shfl_xor(acc, off);
        if (lane == 0) out[b * 2 + wvv] = acc + fc2b[wvv];
    }
}

extern "C" void kernel_launch(void* const* d_in, const int* in_sizes, int n_in,
                              void* d_out, int out_size, void* d_ws, size_t ws_size,
                              hipStream_t stream)
{
    const int*   q1     = (const int*)d_in[0];
    const int*   q2     = (const int*)d_in[1];
    const int*   q1_len = (const int*)d_in[2];
    const int*   q2_len = (const int*)d_in[3];
    const float* emb    = (const float*)d_in[4];
    const float* conv_w = (const float*)d_in[5];
    const float* conv_b = (const float*)d_in[6];
    const float* fc0_w  = (const float*)d_in[7];
    const float* fc0_b  = (const float*)d_in[8];
    const float* fc1_w  = (const float*)d_in[9];
    const float* fc1_b  = (const float*)d_in[10];
    const float* fc2_w  = (const float*)d_in[11];
    const float* fc2_b  = (const float*)d_in[12];
    const float* att_w  = (const float*)d_in[13];
    const float* att_b  = (const float*)d_in[14];

    float* ws  = (float*)d_ws;
    float* r1  = ws;
    float* r2  = ws + 921600;
    float* s1p = ws + 1843200;
    float* s2p = ws + 4608000;
    float* s1  = ws + 7372800;
    float* s2  = ws + 8294400;
    float* h1  = ws + 9216000;
    float* h2  = ws + 9235200;
    float* wt  = ws + 9254400;
    float* out = (float*)d_out;

    hipLaunchKernelGGL(k0_transpose_w, dim3((3 * E_ * E_ + 255) / 256), dim3(256), 0, stream,
                       conv_w, wt);
    hipLaunchKernelGGL(k1_encode, dim3(256), dim3(320), 0, stream,
                       q1, q2, emb, wt, conv_b, r1, r2);
    hipLaunchKernelGGL(k2_joint, dim3(9, 64), dim3(256), 0, stream,
                       r1, r2, q1_len, q2_len, fc0_w, s1p, s2p);
    hipLaunchKernelGGL(k3_combine, dim3((64 * 48 * 300 + 255) / 256), dim3(256), 0, stream,
                       s1p, s2p, fc0_b, s1, s2);
    hipLaunchKernelGGL(k4_pool, dim3(128), dim3(64), 0, stream,
                       r1, r2, s1, s2, q1_len, q2_len, att_w, att_b, h1, h2);
    hipLaunchKernelGGL(k5_mlp, dim3(64), dim3(256), 0, stream,
                       h1, h2, fc1_w, fc1_b, fc2_w, fc2_b, out);
}